// Round 1
// baseline (1137.769 us; speedup 1.0000x reference)
//
#include <hip/hip_runtime.h>
#include <hip/hip_bf16.h>

// Problem constants
constexpr int B_ = 4, N_ = 2048, D_ = 768, OUT_ = 768;
constexpr int M_ = B_ * N_;  // 8192 rows for the fused QKV GEMM

__device__ __forceinline__ float bf2f(unsigned int u16) {
    return __uint_as_float(u16 << 16);
}

// ---------------------------------------------------------------------------
// Kernel 1: QKV projection. C[s,m,n] = sum_d x[m,d] * W[s,d,n], output bf16.
// grid (M/64, OUT/64, 3), block 256. 64x64 tile, BK=16, 4x4 microtile.
// ---------------------------------------------------------------------------
__global__ __launch_bounds__(256)
void qkv_gemm(const float* __restrict__ x, const float* __restrict__ w,
              __hip_bfloat16* __restrict__ qkv) {
    __shared__ float As[16][68];  // [k][m], pad 68 -> 16B-aligned rows, 2-way max
    __shared__ float Bs[16][68];  // [k][n]

    const int s  = blockIdx.z;
    const int m0 = blockIdx.x * 64;
    const int n0 = blockIdx.y * 64;
    const float* wp = w + (size_t)s * D_ * OUT_;
    __hip_bfloat16* out = qkv + (size_t)s * M_ * OUT_;

    const int tid = threadIdx.x;
    const int tx = tid & 15, ty = tid >> 4;

    float acc[4][4] = {};

    for (int k0 = 0; k0 < D_; k0 += 16) {
        {   // A tile: 64 rows x 16 k
            const int c = tid & 15, r = tid >> 4;
#pragma unroll
            for (int i = 0; i < 4; ++i)
                As[c][r + 16 * i] = x[(size_t)(m0 + r + 16 * i) * D_ + k0 + c];
        }
        {   // B tile: 16 k x 64 n
            const int n = tid & 63, kk = tid >> 6;
#pragma unroll
            for (int i = 0; i < 4; ++i)
                Bs[kk + 4 * i][n] = wp[(size_t)(k0 + kk + 4 * i) * OUT_ + n0 + n];
        }
        __syncthreads();
#pragma unroll
        for (int k = 0; k < 16; ++k) {
            float a[4], b[4];
#pragma unroll
            for (int i = 0; i < 4; ++i) a[i] = As[k][4 * ty + i];
#pragma unroll
            for (int i = 0; i < 4; ++i) b[i] = Bs[k][4 * tx + i];
#pragma unroll
            for (int i = 0; i < 4; ++i)
#pragma unroll
                for (int j = 0; j < 4; ++j) acc[i][j] += a[i] * b[j];
        }
        __syncthreads();
    }

#pragma unroll
    for (int i = 0; i < 4; ++i) {
        const int m = m0 + 4 * ty + i;
#pragma unroll
        for (int j = 0; j < 4; ++j) {
            const int n = n0 + 4 * tx + j;
            out[(size_t)m * OUT_ + n] = __float2bfloat16(acc[i][j]);
        }
    }
}

// ---------------------------------------------------------------------------
// Kernel 2: scores. S[b,i,j] = 0.125 * dot(q[b,i,:], k[b,j,:]) over OUT_=768.
// Both operands row-major along d (a B^T GEMM). bf16 in, fp32 out.
// grid (N/64, N/64, B), block 256. BK=32.
// ---------------------------------------------------------------------------
__global__ __launch_bounds__(256)
void scores_gemm(const __hip_bfloat16* __restrict__ q,
                 const __hip_bfloat16* __restrict__ k,
                 float* __restrict__ S) {
    __shared__ float As[32][68];  // [k][i]
    __shared__ float Bs[32][68];  // [k][j]

    const int b  = blockIdx.z;
    const int i0 = blockIdx.x * 64;
    const int j0 = blockIdx.y * 64;
    const __hip_bfloat16* qb = q + (size_t)b * N_ * OUT_;
    const __hip_bfloat16* kb = k + (size_t)b * N_ * OUT_;
    float* Sb = S + (size_t)b * N_ * N_;

    const int tid = threadIdx.x;
    const int tx = tid & 15, ty = tid >> 4;

    float acc[4][4] = {};

    for (int k0 = 0; k0 < OUT_; k0 += 32) {
        // 64 rows x 32 k = 64 x 16 uints (bf16 pairs); 4 uints per thread
#pragma unroll
        for (int i = 0; i < 4; ++i) {
            const int u = tid + 256 * i;
            const int row = u >> 4, kc = u & 15;
            const unsigned int pq =
                *(const unsigned int*)(qb + (size_t)(i0 + row) * OUT_ + k0 + 2 * kc);
            As[2 * kc][row]     = bf2f(pq & 0xffffu);
            As[2 * kc + 1][row] = bf2f(pq >> 16);
            const unsigned int pk =
                *(const unsigned int*)(kb + (size_t)(j0 + row) * OUT_ + k0 + 2 * kc);
            Bs[2 * kc][row]     = bf2f(pk & 0xffffu);
            Bs[2 * kc + 1][row] = bf2f(pk >> 16);
        }
        __syncthreads();
#pragma unroll
        for (int kk = 0; kk < 32; ++kk) {
            float a[4], bb[4];
#pragma unroll
            for (int i = 0; i < 4; ++i) a[i] = As[kk][4 * ty + i];
#pragma unroll
            for (int i = 0; i < 4; ++i) bb[i] = Bs[kk][4 * tx + i];
#pragma unroll
            for (int i = 0; i < 4; ++i)
#pragma unroll
                for (int j = 0; j < 4; ++j) acc[i][j] += a[i] * bb[j];
        }
        __syncthreads();
    }

#pragma unroll
    for (int i = 0; i < 4; ++i) {
        const int ii = i0 + 4 * ty + i;
#pragma unroll
        for (int j = 0; j < 4; ++j) {
            const int jj = j0 + 4 * tx + j;
            Sb[(size_t)ii * N_ + jj] = acc[i][j] * 0.125f;
        }
    }
}

// ---------------------------------------------------------------------------
// Kernel 3: in-place row softmax over S rows of length N_=2048.
// One block (256 threads) per row; float4 loads (512 float4 per row).
// ---------------------------------------------------------------------------
__global__ __launch_bounds__(256)
void softmax_rows(float* __restrict__ S) {
    __shared__ float red[8];
    const int row = blockIdx.x;
    float* p = S + (size_t)row * (size_t)N_;
    const int tid = threadIdx.x;

    float4* p4 = (float4*)p;
    float4 a = p4[tid];
    float4 b = p4[tid + 256];

    float m = fmaxf(fmaxf(fmaxf(a.x, a.y), fmaxf(a.z, a.w)),
                    fmaxf(fmaxf(b.x, b.y), fmaxf(b.z, b.w)));
#pragma unroll
    for (int off = 32; off > 0; off >>= 1) m = fmaxf(m, __shfl_xor(m, off, 64));
    const int wid = tid >> 6, lane = tid & 63;
    if (lane == 0) red[wid] = m;
    __syncthreads();
    if (tid == 0) red[4] = fmaxf(fmaxf(red[0], red[1]), fmaxf(red[2], red[3]));
    __syncthreads();
    m = red[4];

    a.x = __expf(a.x - m); a.y = __expf(a.y - m);
    a.z = __expf(a.z - m); a.w = __expf(a.w - m);
    b.x = __expf(b.x - m); b.y = __expf(b.y - m);
    b.z = __expf(b.z - m); b.w = __expf(b.w - m);

    float s = a.x + a.y + a.z + a.w + b.x + b.y + b.z + b.w;
#pragma unroll
    for (int off = 32; off > 0; off >>= 1) s += __shfl_xor(s, off, 64);
    if (lane == 0) red[wid] = s;
    __syncthreads();
    if (tid == 0) red[5] = red[0] + red[1] + red[2] + red[3];
    __syncthreads();
    const float r = 1.0f / red[5];

    a.x *= r; a.y *= r; a.z *= r; a.w *= r;
    b.x *= r; b.y *= r; b.z *= r; b.w *= r;
    p4[tid] = a;
    p4[tid + 256] = b;
}

// ---------------------------------------------------------------------------
// Kernel 4: out[b,i,n] = sum_j P[b,i,j] * v[b,j,n]. fp32 P, bf16 v, fp32 out.
// grid (N/64, OUT/64, B), block 256. BK=16.
// ---------------------------------------------------------------------------
__global__ __launch_bounds__(256)
void pv_gemm(const float* __restrict__ S, const __hip_bfloat16* __restrict__ v,
             float* __restrict__ out) {
    __shared__ float As[16][68];  // [j][i]
    __shared__ float Bs[16][68];  // [j][n]

    const int b  = blockIdx.z;
    const int i0 = blockIdx.x * 64;
    const int n0 = blockIdx.y * 64;
    const float* Pb = S + (size_t)b * N_ * N_;
    const __hip_bfloat16* vb = v + (size_t)b * N_ * OUT_;
    float* ob = out + (size_t)b * N_ * OUT_;

    const int tid = threadIdx.x;
    const int tx = tid & 15, ty = tid >> 4;

    float acc[4][4] = {};

    for (int k0 = 0; k0 < N_; k0 += 16) {
        {
            const int c = tid & 15, r = tid >> 4;
#pragma unroll
            for (int i = 0; i < 4; ++i)
                As[c][r + 16 * i] = Pb[(size_t)(i0 + r + 16 * i) * N_ + k0 + c];
        }
        {
            const int n = tid & 63, jj = tid >> 6;
#pragma unroll
            for (int i = 0; i < 4; ++i)
                Bs[jj + 4 * i][n] =
                    __bfloat162float(vb[(size_t)(k0 + jj + 4 * i) * OUT_ + n0 + n]);
        }
        __syncthreads();
#pragma unroll
        for (int k = 0; k < 16; ++k) {
            float a[4], bb[4];
#pragma unroll
            for (int i = 0; i < 4; ++i) a[i] = As[k][4 * ty + i];
#pragma unroll
            for (int i = 0; i < 4; ++i) bb[i] = Bs[k][4 * tx + i];
#pragma unroll
            for (int i = 0; i < 4; ++i)
#pragma unroll
                for (int j = 0; j < 4; ++j) acc[i][j] += a[i] * bb[j];
        }
        __syncthreads();
    }

#pragma unroll
    for (int i = 0; i < 4; ++i) {
        const int ii = i0 + 4 * ty + i;
#pragma unroll
        for (int j = 0; j < 4; ++j) {
            const int nn = n0 + 4 * tx + j;
            ob[(size_t)ii * OUT_ + nn] = acc[i][j];
        }
    }
}

// ---------------------------------------------------------------------------
// Launch. ws layout: [qkv bf16: 3*M*OUT*2 = 37.75 MB][S fp32: B*N*N*4 = 67.1 MB]
// Total 100 MB.
// ---------------------------------------------------------------------------
extern "C" void kernel_launch(void* const* d_in, const int* in_sizes, int n_in,
                              void* d_out, int out_size, void* d_ws, size_t ws_size,
                              hipStream_t stream) {
    const float* x = (const float*)d_in[0];
    const float* w = (const float*)d_in[1];
    float* out = (float*)d_out;

    char* ws = (char*)d_ws;
    __hip_bfloat16* qkv = (__hip_bfloat16*)ws;
    float* S = (float*)(ws + (size_t)3 * M_ * OUT_ * sizeof(__hip_bfloat16));

    const __hip_bfloat16* q = qkv;
    const __hip_bfloat16* k = qkv + (size_t)M_ * OUT_;
    const __hip_bfloat16* v = qkv + (size_t)2 * M_ * OUT_;

    dim3 blk(256);
    qkv_gemm<<<dim3(M_ / 64, OUT_ / 64, 3), blk, 0, stream>>>(x, w, qkv);
    scores_gemm<<<dim3(N_ / 64, N_ / 64, B_), blk, 0, stream>>>(q, k, S);
    softmax_rows<<<dim3(B_ * N_), blk, 0, stream>>>(S);
    pv_gemm<<<dim3(N_ / 64, OUT_ / 64, B_), blk, 0, stream>>>(S, v, out);
}

// Round 2
// 245.765 us; speedup vs baseline: 4.6295x; 4.6295x over previous
//
#include <hip/hip_runtime.h>
#include <hip/hip_bf16.h>

// Problem constants
constexpr int B_ = 4, N_ = 2048, D_ = 768, OUT_ = 768;
constexpr int M_ = B_ * N_;  // 8192 rows for the fused QKV GEMM

typedef __attribute__((ext_vector_type(8))) short short8;   // 8 bf16 (4 VGPRs)
typedef __attribute__((ext_vector_type(4))) float floatx4;  // MFMA C/D frag

__device__ __forceinline__ unsigned short f2bfu(float f) {
    union { __hip_bfloat16 b; unsigned short u; } cv;
    cv.b = __float2bfloat16(f);
    return cv.u;
}

#define GLOAD_LDS16(g, l)                                                     \
    __builtin_amdgcn_global_load_lds(                                         \
        (const __attribute__((address_space(1))) void*)(g),                   \
        (__attribute__((address_space(3))) void*)(l), 16, 0, 0)

// ---------------------------------------------------------------------------
// Shared NT-GEMM core: C[128x128] += A[m0..m0+128, :K] * B[n0..n0+128, :K]^T
// A, B row-major along K (both lda/ldb multiples of 32, 16B-aligned rows).
// 256 threads = 4 waves in a 2x2 wave grid; each wave does 4x4 MFMA tiles.
// LDS tiles are contiguous 128x32 bf16 (no padding: global_load_lds writes
// wave-uniform-base + lane*16B).
// ---------------------------------------------------------------------------
__device__ __forceinline__ void gemm_core_nt(
    const __hip_bfloat16* __restrict__ a_base, int lda,
    const __hip_bfloat16* __restrict__ b_base, int ldb,
    int m0, int n0, int K,
    __hip_bfloat16* As, __hip_bfloat16* Bs,
    floatx4 acc[4][4]) {
    const int tid  = threadIdx.x;
    const int wave = tid >> 6, lane = tid & 63;
    const int wm = (wave >> 1) << 6, wn = (wave & 1) << 6;
    const int lrow = lane & 15, kq = lane >> 4;

    for (int k0 = 0; k0 < K; k0 += 32) {
        // stage A-tile: 512 16B units; unit u -> row u>>2, k-chunk (u&3)*8
#pragma unroll
        for (int i = 0; i < 2; ++i) {
            const int u = i * 256 + tid;
            const __hip_bfloat16* g =
                a_base + (size_t)(m0 + (u >> 2)) * lda + k0 + (u & 3) * 8;
            GLOAD_LDS16(g, As + (size_t)(i * 256 + wave * 64) * 8);
        }
#pragma unroll
        for (int i = 0; i < 2; ++i) {
            const int u = i * 256 + tid;
            const __hip_bfloat16* g =
                b_base + (size_t)(n0 + (u >> 2)) * ldb + k0 + (u & 3) * 8;
            GLOAD_LDS16(g, Bs + (size_t)(i * 256 + wave * 64) * 8);
        }
        __syncthreads();  // drains vmcnt for the per-wave global_load_lds too

        short8 af[4], bfr[4];
#pragma unroll
        for (int t = 0; t < 4; ++t)
            af[t] = *(const short8*)(As + (wm + t * 16 + lrow) * 32 + kq * 8);
#pragma unroll
        for (int t = 0; t < 4; ++t)
            bfr[t] = *(const short8*)(Bs + (wn + t * 16 + lrow) * 32 + kq * 8);
#pragma unroll
        for (int mi = 0; mi < 4; ++mi)
#pragma unroll
            for (int ni = 0; ni < 4; ++ni)
                acc[mi][ni] = __builtin_amdgcn_mfma_f32_16x16x32_bf16(
                    af[mi], bfr[ni], acc[mi][ni], 0, 0, 0);
        __syncthreads();
    }
}

// ---------------------------------------------------------------------------
// Kernel 0a: fp32 x -> bf16 xb (8 elements/thread)
// ---------------------------------------------------------------------------
__global__ __launch_bounds__(256)
void convert_x(const float* __restrict__ x, __hip_bfloat16* __restrict__ xb) {
    const size_t i = (size_t)blockIdx.x * 2048 + (size_t)threadIdx.x * 8;
    float4 a = *(const float4*)(x + i);
    float4 b = *(const float4*)(x + i + 4);
    ushort4 pa = make_ushort4(f2bfu(a.x), f2bfu(a.y), f2bfu(a.z), f2bfu(a.w));
    ushort4 pb = make_ushort4(f2bfu(b.x), f2bfu(b.y), f2bfu(b.z), f2bfu(b.w));
    *(ushort4*)((unsigned short*)xb + i) = pa;
    *(ushort4*)((unsigned short*)xb + i + 4) = pb;
}

// ---------------------------------------------------------------------------
// Kernel 0b: w[s][d][o] fp32 -> wt[s][o][d] bf16 (32x32 LDS tile transpose)
// ---------------------------------------------------------------------------
__global__ __launch_bounds__(256)
void transpose_w(const float* __restrict__ w, __hip_bfloat16* __restrict__ wt) {
    __shared__ float t[32][33];
    const int s = blockIdx.z;
    const int d0 = blockIdx.x * 32, o0 = blockIdx.y * 32;
    const int tx = threadIdx.x, ty = threadIdx.y;  // 32 x 8
    const float* ws = w + (size_t)s * D_ * OUT_;
    __hip_bfloat16* wts = wt + (size_t)s * OUT_ * D_;
#pragma unroll
    for (int i = 0; i < 4; ++i)
        t[ty + 8 * i][tx] = ws[(size_t)(d0 + ty + 8 * i) * OUT_ + o0 + tx];
    __syncthreads();
#pragma unroll
    for (int i = 0; i < 4; ++i)
        wts[(size_t)(o0 + ty + 8 * i) * D_ + d0 + tx] =
            __float2bfloat16(t[tx][ty + 8 * i]);
}

// ---------------------------------------------------------------------------
// Kernel 1: QKV projection (NT, bf16 MFMA). grid (64, 6, 3).
// s=0 -> q[m][n], s=1 -> k[m][n], s=2 -> vt[b][n][j] (transposed write).
// ---------------------------------------------------------------------------
__global__ __launch_bounds__(256)
void qkv_mfma(const __hip_bfloat16* __restrict__ xb,
              const __hip_bfloat16* __restrict__ wt,
              __hip_bfloat16* __restrict__ q, __hip_bfloat16* __restrict__ k,
              __hip_bfloat16* __restrict__ vt) {
    __shared__ __hip_bfloat16 As[128 * 32], Bs[128 * 32];
    const int s = blockIdx.z;
    const int m0 = blockIdx.x * 128, n0 = blockIdx.y * 128;
    floatx4 acc[4][4] = {};
    gemm_core_nt(xb, D_, wt + (size_t)s * OUT_ * D_, D_, m0, n0, D_, As, Bs, acc);

    const int tid = threadIdx.x, wave = tid >> 6, lane = tid & 63;
    const int wm = (wave >> 1) << 6, wn = (wave & 1) << 6;
    const int lrow = lane & 15, kq = lane >> 4;

    if (s < 2) {
        __hip_bfloat16* out = (s == 0) ? q : k;
#pragma unroll
        for (int mi = 0; mi < 4; ++mi)
#pragma unroll
            for (int ni = 0; ni < 4; ++ni) {
                const int n = n0 + wn + ni * 16 + lrow;
#pragma unroll
                for (int r = 0; r < 4; ++r) {
                    const int m = m0 + wm + mi * 16 + kq * 4 + r;
                    out[(size_t)m * OUT_ + n] = __float2bfloat16(acc[mi][ni][r]);
                }
            }
    } else {
#pragma unroll
        for (int mi = 0; mi < 4; ++mi) {
            const int mb = m0 + wm + mi * 16 + kq * 4;
            const int b = mb >> 11, j = mb & 2047;
#pragma unroll
            for (int ni = 0; ni < 4; ++ni) {
                const int n = n0 + wn + ni * 16 + lrow;
                ushort4 pk = make_ushort4(
                    f2bfu(acc[mi][ni][0]), f2bfu(acc[mi][ni][1]),
                    f2bfu(acc[mi][ni][2]), f2bfu(acc[mi][ni][3]));
                *(ushort4*)(vt + ((size_t)b * OUT_ + n) * (size_t)N_ + j) = pk;
            }
        }
    }
}

// ---------------------------------------------------------------------------
// Kernel 2: scores (NT, bf16 MFMA). grid (16, 16, 4). S fp32 = q.k^T / 8.
// ---------------------------------------------------------------------------
__global__ __launch_bounds__(256)
void scores_mfma(const __hip_bfloat16* __restrict__ q,
                 const __hip_bfloat16* __restrict__ k,
                 float* __restrict__ S) {
    __shared__ __hip_bfloat16 As[128 * 32], Bs[128 * 32];
    const int b = blockIdx.z;
    const int m0 = blockIdx.x * 128, n0 = blockIdx.y * 128;
    floatx4 acc[4][4] = {};
    gemm_core_nt(q + (size_t)b * N_ * OUT_, OUT_, k + (size_t)b * N_ * OUT_,
                 OUT_, m0, n0, OUT_, As, Bs, acc);

    const int tid = threadIdx.x, wave = tid >> 6, lane = tid & 63;
    const int wm = (wave >> 1) << 6, wn = (wave & 1) << 6;
    const int lrow = lane & 15, kq = lane >> 4;
    float* Sb = S + (size_t)b * N_ * N_;
#pragma unroll
    for (int mi = 0; mi < 4; ++mi)
#pragma unroll
        for (int ni = 0; ni < 4; ++ni) {
            const int j = n0 + wn + ni * 16 + lrow;
#pragma unroll
            for (int r = 0; r < 4; ++r) {
                const int i = m0 + wm + mi * 16 + kq * 4 + r;
                Sb[(size_t)i * N_ + j] = acc[mi][ni][r] * 0.125f;
            }
        }
}

// ---------------------------------------------------------------------------
// Kernel 3: row softmax, fp32 in -> bf16 P written in-place at row start.
// P row stride = 4096 bf16 elements (the fp32 row footprint).
// Safe in-place: all reads complete before the post-sum barrier; writes after.
// ---------------------------------------------------------------------------
__global__ __launch_bounds__(256)
void softmax_rows_bf16(float* __restrict__ S) {
    __shared__ float red[8];
    const int row = blockIdx.x;
    float* p = S + (size_t)row * (size_t)N_;
    const int tid = threadIdx.x;

    float4* p4 = (float4*)p;
    float4 a = p4[tid];
    float4 b = p4[tid + 256];

    float m = fmaxf(fmaxf(fmaxf(a.x, a.y), fmaxf(a.z, a.w)),
                    fmaxf(fmaxf(b.x, b.y), fmaxf(b.z, b.w)));
#pragma unroll
    for (int off = 32; off > 0; off >>= 1) m = fmaxf(m, __shfl_xor(m, off, 64));
    const int wid = tid >> 6, lane = tid & 63;
    if (lane == 0) red[wid] = m;
    __syncthreads();
    if (tid == 0) red[4] = fmaxf(fmaxf(red[0], red[1]), fmaxf(red[2], red[3]));
    __syncthreads();
    m = red[4];

    a.x = __expf(a.x - m); a.y = __expf(a.y - m);
    a.z = __expf(a.z - m); a.w = __expf(a.w - m);
    b.x = __expf(b.x - m); b.y = __expf(b.y - m);
    b.z = __expf(b.z - m); b.w = __expf(b.w - m);

    float s = a.x + a.y + a.z + a.w + b.x + b.y + b.z + b.w;
#pragma unroll
    for (int off = 32; off > 0; off >>= 1) s += __shfl_xor(s, off, 64);
    if (lane == 0) red[wid] = s;
    __syncthreads();
    if (tid == 0) red[5] = red[0] + red[1] + red[2] + red[3];
    __syncthreads();  // also guarantees every lane's reads precede any write
    const float r = 1.0f / red[5];

    ushort4* o4 = (ushort4*)p;
    o4[tid] = make_ushort4(f2bfu(a.x * r), f2bfu(a.y * r),
                           f2bfu(a.z * r), f2bfu(a.w * r));
    o4[tid + 256] = make_ushort4(f2bfu(b.x * r), f2bfu(b.y * r),
                                 f2bfu(b.z * r), f2bfu(b.w * r));
}

// ---------------------------------------------------------------------------
// Kernel 4: out = P.V (NT, bf16 MFMA): A = P (lda 4096), B = vt[b][o][j].
// grid (16, 6, 4). fp32 output.
// ---------------------------------------------------------------------------
__global__ __launch_bounds__(256)
void pv_mfma(const __hip_bfloat16* __restrict__ P,
             const __hip_bfloat16* __restrict__ vt,
             float* __restrict__ out) {
    __shared__ __hip_bfloat16 As[128 * 32], Bs[128 * 32];
    const int b = blockIdx.z;
    const int m0 = blockIdx.x * 128, n0 = blockIdx.y * 128;
    floatx4 acc[4][4] = {};
    gemm_core_nt(P + (size_t)b * N_ * 4096, 4096,
                 vt + (size_t)b * OUT_ * N_, N_, m0, n0, N_, As, Bs, acc);

    const int tid = threadIdx.x, wave = tid >> 6, lane = tid & 63;
    const int wm = (wave >> 1) << 6, wn = (wave & 1) << 6;
    const int lrow = lane & 15, kq = lane >> 4;
#pragma unroll
    for (int mi = 0; mi < 4; ++mi)
#pragma unroll
        for (int ni = 0; ni < 4; ++ni) {
            const int n = n0 + wn + ni * 16 + lrow;
#pragma unroll
            for (int r = 0; r < 4; ++r) {
                const int i = m0 + wm + mi * 16 + kq * 4 + r;
                out[((size_t)b * N_ + i) * OUT_ + n] = acc[mi][ni][r];
            }
        }
}

// ---------------------------------------------------------------------------
// ws layout (104,857,600 B total — same footprint as round 1, proven safe):
//   [0        : q  bf16 12.6MB][12.6MB: k bf16][25.2MB: vt bf16]
//   [37.75MB  : xb bf16 12.6MB][50.3MB: wt bf16 3.5MB]   <- dead after qkv
//   [37.75MB  : S fp32 67.1MB]                           <- overlays xb/wt
// ---------------------------------------------------------------------------
extern "C" void kernel_launch(void* const* d_in, const int* in_sizes, int n_in,
                              void* d_out, int out_size, void* d_ws, size_t ws_size,
                              hipStream_t stream) {
    const float* x = (const float*)d_in[0];
    const float* w = (const float*)d_in[1];
    float* out = (float*)d_out;

    char* ws = (char*)d_ws;
    __hip_bfloat16* q  = (__hip_bfloat16*)ws;
    __hip_bfloat16* k  = q + (size_t)M_ * OUT_;
    __hip_bfloat16* vt = k + (size_t)M_ * OUT_;
    __hip_bfloat16* xb = vt + (size_t)M_ * OUT_;
    __hip_bfloat16* wt = xb + (size_t)M_ * D_;
    float* S = (float*)(ws + (size_t)3 * M_ * OUT_ * sizeof(__hip_bfloat16));

    convert_x<<<dim3(M_ * D_ / 2048), dim3(256), 0, stream>>>(x, xb);
    transpose_w<<<dim3(24, 24, 3), dim3(32, 8), 0, stream>>>(w, wt);
    qkv_mfma<<<dim3(M_ / 128, OUT_ / 128, 3), dim3(256), 0, stream>>>(xb, wt, q, k, vt);
    scores_mfma<<<dim3(N_ / 128, N_ / 128, B_), dim3(256), 0, stream>>>(q, k, S);
    softmax_rows_bf16<<<dim3(M_), dim3(256), 0, stream>>>(S);
    pv_mfma<<<dim3(N_ / 128, OUT_ / 128, B_), dim3(256), 0, stream>>>(
        (const __hip_bfloat16*)S, vt, out);
}

// Round 3
// 215.015 us; speedup vs baseline: 5.2916x; 1.1430x over previous
//
#include <hip/hip_runtime.h>
#include <hip/hip_bf16.h>

// Problem constants
constexpr int B_ = 4, N_ = 2048, D_ = 768, OUT_ = 768;
constexpr int M_ = B_ * N_;  // 8192 rows for the fused QKV GEMM

typedef __attribute__((ext_vector_type(8))) short short8;   // 8 bf16 (4 VGPRs)
typedef __attribute__((ext_vector_type(4))) float floatx4;  // MFMA C/D frag

__device__ __forceinline__ unsigned short f2bfu(float f) {
    union { __hip_bfloat16 b; unsigned short u; } cv;
    cv.b = __float2bfloat16(f);
    return cv.u;
}

#define GLOAD_LDS16(g, l)                                                     \
    __builtin_amdgcn_global_load_lds(                                         \
        (const __attribute__((address_space(1))) void*)(g),                   \
        (__attribute__((address_space(3))) void*)(l), 16, 0, 0)

// ---------------------------------------------------------------------------
// NT-GEMM core, BK=64, XOR-swizzled LDS to kill frag-read bank conflicts.
// C[BM x 128] += A[m0.., :K] * B[n0.., :K]^T, A/B row-major along K.
// LDS layout: [row][slot], slot = chunk ^ (row&7), chunk = 16B k-group (8 of
// them per 64-K row). Staging is still wave-uniform-contiguous (required by
// global_load_lds); the XOR only permutes chunks *within* a row, so global
// reads stay fully coalesced (whole 128B rows covered).
// Frag reads: lanes 0..15 hit slots lrow&7 ^ kq -> all 32 banks, 2-way max.
// 256 threads = 2x2 waves; wave tile (BM/2) x 64; BM in {64,128}.
// ---------------------------------------------------------------------------
template <int BM>
__device__ __forceinline__ void gemm_core(
    const __hip_bfloat16* __restrict__ a_base, int lda,
    const __hip_bfloat16* __restrict__ b_base, int ldb,
    int m0, int n0, int K,
    __hip_bfloat16* As, __hip_bfloat16* Bs,
    floatx4 (&acc)[BM / 32][4]) {
    constexpr int MF = BM / 32;  // m-frags per wave; also A staging insts
    const int tid  = threadIdx.x;
    const int wave = tid >> 6, lane = tid & 63;
    const int wm = (wave >> 1) * (BM / 2), wn = (wave & 1) * 64;
    const int lrow = lane & 15, kq = lane >> 4;
    const int sw = lrow & 7;

    for (int k0 = 0; k0 < K; k0 += 64) {
        // A-tile: BM rows x 64 bf16 = BM*8 16B units, MF insts/thread
#pragma unroll
        for (int i = 0; i < MF; ++i) {
            const int u = i * 256 + tid;
            const int row = u >> 3, cg = (u & 7) ^ (row & 7);
            const __hip_bfloat16* g =
                a_base + (size_t)(m0 + row) * lda + k0 + cg * 8;
            GLOAD_LDS16(g, As + (size_t)(i * 256 + wave * 64) * 8);
        }
        // B-tile: 128 rows x 64 bf16, 4 insts/thread
#pragma unroll
        for (int i = 0; i < 4; ++i) {
            const int u = i * 256 + tid;
            const int row = u >> 3, cg = (u & 7) ^ (row & 7);
            const __hip_bfloat16* g =
                b_base + (size_t)(n0 + row) * ldb + k0 + cg * 8;
            GLOAD_LDS16(g, Bs + (size_t)(i * 256 + wave * 64) * 8);
        }
        __syncthreads();

#pragma unroll
        for (int s = 0; s < 2; ++s) {  // two 32-K MFMA steps per stage
            short8 af[MF], bfr[4];
#pragma unroll
            for (int t = 0; t < MF; ++t) {
                const int row = wm + t * 16 + lrow;
                const int slot = (s * 4 + kq) ^ sw;
                af[t] = *(const short8*)(As + row * 64 + slot * 8);
            }
#pragma unroll
            for (int t = 0; t < 4; ++t) {
                const int row = wn + t * 16 + lrow;
                const int slot = (s * 4 + kq) ^ sw;
                bfr[t] = *(const short8*)(Bs + row * 64 + slot * 8);
            }
#pragma unroll
            for (int mi = 0; mi < MF; ++mi)
#pragma unroll
                for (int ni = 0; ni < 4; ++ni)
                    acc[mi][ni] = __builtin_amdgcn_mfma_f32_16x16x32_bf16(
                        af[mi], bfr[ni], acc[mi][ni], 0, 0, 0);
        }
        __syncthreads();
    }
}

// ---------------------------------------------------------------------------
// Kernel 0a: fp32 x -> bf16 xb (8 elements/thread)
// ---------------------------------------------------------------------------
__global__ __launch_bounds__(256)
void convert_x(const float* __restrict__ x, __hip_bfloat16* __restrict__ xb) {
    const size_t i = (size_t)blockIdx.x * 2048 + (size_t)threadIdx.x * 8;
    float4 a = *(const float4*)(x + i);
    float4 b = *(const float4*)(x + i + 4);
    ushort4 pa = make_ushort4(f2bfu(a.x), f2bfu(a.y), f2bfu(a.z), f2bfu(a.w));
    ushort4 pb = make_ushort4(f2bfu(b.x), f2bfu(b.y), f2bfu(b.z), f2bfu(b.w));
    *(ushort4*)((unsigned short*)xb + i) = pa;
    *(ushort4*)((unsigned short*)xb + i + 4) = pb;
}

// ---------------------------------------------------------------------------
// Kernel 0b: w[s][d][o] fp32 -> wt[s][o][d] bf16 (32x32 LDS tile transpose)
// ---------------------------------------------------------------------------
__global__ __launch_bounds__(256)
void transpose_w(const float* __restrict__ w, __hip_bfloat16* __restrict__ wt) {
    __shared__ float t[32][33];
    const int s = blockIdx.z;
    const int d0 = blockIdx.x * 32, o0 = blockIdx.y * 32;
    const int tx = threadIdx.x, ty = threadIdx.y;  // 32 x 8
    const float* ws = w + (size_t)s * D_ * OUT_;
    __hip_bfloat16* wts = wt + (size_t)s * OUT_ * D_;
#pragma unroll
    for (int i = 0; i < 4; ++i)
        t[ty + 8 * i][tx] = ws[(size_t)(d0 + ty + 8 * i) * OUT_ + o0 + tx];
    __syncthreads();
#pragma unroll
    for (int i = 0; i < 4; ++i)
        wts[(size_t)(o0 + ty + 8 * i) * D_ + d0 + tx] =
            __float2bfloat16(t[tx][ty + 8 * i]);
}

// ---------------------------------------------------------------------------
// Kernel 1: QKV projection (NT, bf16 MFMA, 128x128, BK=64). grid (64, 6, 3).
// Epilogue: LDS roundtrip (row stride 136 shorts -> conflict-free, 16B
// aligned) then coalesced short8 stores. s=2 writes v TRANSPOSED (vt[b][o][j])
// via the [n][m] LDS layout — no scattered global stores.
// ---------------------------------------------------------------------------
__global__ __launch_bounds__(256)
void qkv_mfma(const __hip_bfloat16* __restrict__ xb,
              const __hip_bfloat16* __restrict__ wt,
              __hip_bfloat16* __restrict__ q, __hip_bfloat16* __restrict__ k,
              __hip_bfloat16* __restrict__ vt) {
    __shared__ __align__(16) char smem[34816];  // max(32KB loop, 34KB epi)
    __hip_bfloat16* As = (__hip_bfloat16*)smem;
    __hip_bfloat16* Bs = As + 128 * 64;
    const int s = blockIdx.z;
    const int m0 = blockIdx.x * 128, n0 = blockIdx.y * 128;
    floatx4 acc[4][4] = {};
    gemm_core<128>(xb, D_, wt + (size_t)s * OUT_ * D_, D_, m0, n0, D_, As, Bs,
                   acc);

    const int tid = threadIdx.x, wave = tid >> 6, lane = tid & 63;
    const int wm = (wave >> 1) * 64, wn = (wave & 1) * 64;
    const int lrow = lane & 15, kq = lane >> 4;
    unsigned short* E = (unsigned short*)smem;  // 128 rows x 136 shorts

    if (s < 2) {  // E[m][n]
#pragma unroll
        for (int mi = 0; mi < 4; ++mi)
#pragma unroll
            for (int ni = 0; ni < 4; ++ni) {
                const int n = wn + ni * 16 + lrow;
#pragma unroll
                for (int r = 0; r < 4; ++r)
                    E[(wm + mi * 16 + kq * 4 + r) * 136 + n] =
                        f2bfu(acc[mi][ni][r]);
            }
    } else {  // E[n][m] — transpose for vt
#pragma unroll
        for (int mi = 0; mi < 4; ++mi)
#pragma unroll
            for (int ni = 0; ni < 4; ++ni) {
                const int n = wn + ni * 16 + lrow;
#pragma unroll
                for (int r = 0; r < 4; ++r)
                    E[n * 136 + wm + mi * 16 + kq * 4 + r] =
                        f2bfu(acc[mi][ni][r]);
            }
    }
    __syncthreads();

    if (s < 2) {
        __hip_bfloat16* out = (s == 0) ? q : k;
#pragma unroll
        for (int i = 0; i < 8; ++i) {
            const int u = i * 256 + tid, row = u >> 4, c = u & 15;
            short8 v = *(const short8*)(E + row * 136 + c * 8);
            *(short8*)(out + (size_t)(m0 + row) * OUT_ + n0 + c * 8) = v;
        }
    } else {
        const int b = m0 >> 11, j0 = m0 & 2047;
#pragma unroll
        for (int i = 0; i < 8; ++i) {
            const int u = i * 256 + tid, nrow = u >> 4, c = u & 15;
            short8 v = *(const short8*)(E + nrow * 136 + c * 8);
            *(short8*)(vt + ((size_t)b * OUT_ + n0 + nrow) * N_ + j0 + c * 8) =
                v;
        }
    }
}

// ---------------------------------------------------------------------------
// Kernel 2: scores (NT, 128x128, BK=64). grid (16, 16, 4). fp32 dword stores
// are already coalesced (16 lanes x 4B = 64B segments) — no LDS epilogue.
// ---------------------------------------------------------------------------
__global__ __launch_bounds__(256)
void scores_mfma(const __hip_bfloat16* __restrict__ q,
                 const __hip_bfloat16* __restrict__ k,
                 float* __restrict__ S) {
    __shared__ __align__(16) __hip_bfloat16 As[128 * 64];
    __shared__ __align__(16) __hip_bfloat16 Bs[128 * 64];
    const int b = blockIdx.z;
    const int m0 = blockIdx.x * 128, n0 = blockIdx.y * 128;
    floatx4 acc[4][4] = {};
    gemm_core<128>(q + (size_t)b * N_ * OUT_, OUT_,
                   k + (size_t)b * N_ * OUT_, OUT_, m0, n0, OUT_, As, Bs, acc);

    const int tid = threadIdx.x, wave = tid >> 6, lane = tid & 63;
    const int wm = (wave >> 1) * 64, wn = (wave & 1) * 64;
    const int lrow = lane & 15, kq = lane >> 4;
    float* Sb = S + (size_t)b * N_ * N_;
#pragma unroll
    for (int mi = 0; mi < 4; ++mi)
#pragma unroll
        for (int ni = 0; ni < 4; ++ni) {
            const int j = n0 + wn + ni * 16 + lrow;
#pragma unroll
            for (int r = 0; r < 4; ++r) {
                const int i = m0 + wm + mi * 16 + kq * 4 + r;
                Sb[(size_t)i * N_ + j] = acc[mi][ni][r] * 0.125f;
            }
        }
}

// ---------------------------------------------------------------------------
// Kernel 3: row softmax, fp32 in -> bf16 P in-place at row start (stride 4096
// shorts). Reads all complete before the post-sum barrier; writes after.
// ---------------------------------------------------------------------------
__global__ __launch_bounds__(256)
void softmax_rows_bf16(float* __restrict__ S) {
    __shared__ float red[8];
    const int row = blockIdx.x;
    float* p = S + (size_t)row * (size_t)N_;
    const int tid = threadIdx.x;

    float4* p4 = (float4*)p;
    float4 a = p4[tid];
    float4 b = p4[tid + 256];

    float m = fmaxf(fmaxf(fmaxf(a.x, a.y), fmaxf(a.z, a.w)),
                    fmaxf(fmaxf(b.x, b.y), fmaxf(b.z, b.w)));
#pragma unroll
    for (int off = 32; off > 0; off >>= 1) m = fmaxf(m, __shfl_xor(m, off, 64));
    const int wid = tid >> 6, lane = tid & 63;
    if (lane == 0) red[wid] = m;
    __syncthreads();
    if (tid == 0) red[4] = fmaxf(fmaxf(red[0], red[1]), fmaxf(red[2], red[3]));
    __syncthreads();
    m = red[4];

    a.x = __expf(a.x - m); a.y = __expf(a.y - m);
    a.z = __expf(a.z - m); a.w = __expf(a.w - m);
    b.x = __expf(b.x - m); b.y = __expf(b.y - m);
    b.z = __expf(b.z - m); b.w = __expf(b.w - m);

    float s = a.x + a.y + a.z + a.w + b.x + b.y + b.z + b.w;
#pragma unroll
    for (int off = 32; off > 0; off >>= 1) s += __shfl_xor(s, off, 64);
    if (lane == 0) red[wid] = s;
    __syncthreads();
    if (tid == 0) red[5] = red[0] + red[1] + red[2] + red[3];
    __syncthreads();  // all reads precede any write
    const float r = 1.0f / red[5];

    ushort4* o4 = (ushort4*)p;
    o4[tid] = make_ushort4(f2bfu(a.x * r), f2bfu(a.y * r),
                           f2bfu(a.z * r), f2bfu(a.w * r));
    o4[tid + 256] = make_ushort4(f2bfu(b.x * r), f2bfu(b.y * r),
                                 f2bfu(b.z * r), f2bfu(b.w * r));
}

// ---------------------------------------------------------------------------
// Kernel 4: out = P.V (NT, 64x128 tile, BK=64): A = P (lda 4096 shorts),
// B = vt[b][o][j]. grid (32, 6, 4) = 768 blocks (3/CU vs 1.5 at 128-tile).
// ---------------------------------------------------------------------------
__global__ __launch_bounds__(256)
void pv_mfma(const __hip_bfloat16* __restrict__ P,
             const __hip_bfloat16* __restrict__ vt,
             float* __restrict__ out) {
    __shared__ __align__(16) __hip_bfloat16 As[64 * 64];
    __shared__ __align__(16) __hip_bfloat16 Bs[128 * 64];
    const int b = blockIdx.z;
    const int m0 = blockIdx.x * 64, n0 = blockIdx.y * 128;
    floatx4 acc[2][4] = {};
    gemm_core<64>(P + (size_t)b * N_ * 4096, 4096,
                  vt + (size_t)b * OUT_ * N_, N_, m0, n0, N_, As, Bs, acc);

    const int tid = threadIdx.x, wave = tid >> 6, lane = tid & 63;
    const int wm = (wave >> 1) * 32, wn = (wave & 1) * 64;
    const int lrow = lane & 15, kq = lane >> 4;
#pragma unroll
    for (int mi = 0; mi < 2; ++mi)
#pragma unroll
        for (int ni = 0; ni < 4; ++ni) {
            const int n = n0 + wn + ni * 16 + lrow;
#pragma unroll
            for (int r = 0; r < 4; ++r) {
                const int i = m0 + wm + mi * 16 + kq * 4 + r;
                out[((size_t)b * N_ + i) * OUT_ + n] = acc[mi][ni][r];
            }
        }
}

// ---------------------------------------------------------------------------
// ws layout (100 MB, same as round 2):
//   [0: q bf16 12.6MB][12.6: k][25.2: vt][37.75: xb 12.6 | S fp32 67.1]
//   [50.3: wt 3.5MB]  (xb/wt dead once qkv_mfma completes; S overlays them)
// ---------------------------------------------------------------------------
extern "C" void kernel_launch(void* const* d_in, const int* in_sizes, int n_in,
                              void* d_out, int out_size, void* d_ws, size_t ws_size,
                              hipStream_t stream) {
    const float* x = (const float*)d_in[0];
    const float* w = (const float*)d_in[1];
    float* out = (float*)d_out;

    char* ws = (char*)d_ws;
    __hip_bfloat16* q  = (__hip_bfloat16*)ws;
    __hip_bfloat16* k  = q + (size_t)M_ * OUT_;
    __hip_bfloat16* vt = k + (size_t)M_ * OUT_;
    __hip_bfloat16* xb = vt + (size_t)M_ * OUT_;
    __hip_bfloat16* wt = xb + (size_t)M_ * D_;
    float* S = (float*)(ws + (size_t)3 * M_ * OUT_ * sizeof(__hip_bfloat16));

    convert_x<<<dim3(M_ * D_ / 2048), dim3(256), 0, stream>>>(x, xb);
    transpose_w<<<dim3(24, 24, 3), dim3(32, 8), 0, stream>>>(w, wt);
    qkv_mfma<<<dim3(M_ / 128, OUT_ / 128, 3), dim3(256), 0, stream>>>(xb, wt, q, k, vt);
    scores_mfma<<<dim3(N_ / 128, N_ / 128, B_), dim3(256), 0, stream>>>(q, k, S);
    softmax_rows_bf16<<<dim3(M_), dim3(256), 0, stream>>>(S);
    pv_mfma<<<dim3(N_ / 64, OUT_ / 128, B_), dim3(256), 0, stream>>>(
        (const __hip_bfloat16*)S, vt, out);
}